// Round 2
// baseline (324.428 us; speedup 1.0000x reference)
//
#include <hip/hip_runtime.h>

// LocallyConnected2d: x [64,32,64,64] f32, w [1,64,32,62,62,9] f32 -> out [64,64,62,62] f32
// out[b,o,loc] = sum_{i,k} x[b,i,oh+k/3,ow+k%3] * w[o,i,loc,k]
//
// Round-2 design:
//  - block = 8 output locations (one oh row, 8 consecutive ow), all 64 o, all 64 b.
//    Weight for (o,i) is then a CONTIGUOUS 72-float run -> coalesced fetch (fixes the
//    round-1 TA-scatter bottleneck: 64 lines/instr -> dense lines).
//  - lane = b. x read from pre-transposed xT[m][b] -> coalesced 256B, L1-resident.
//  - Weight runs staged into LDS via global_load_lds (deep async queue -> full HBM MLP
//    without register cost). Each wave stages and consumes ONLY its own o-group ->
//    no __syncthreads at all; double-buffered slabs synced with counted vmcnt(16).
//  - Weight consumed as same-address ds_read_b128 broadcasts (1 read : 4 FMAs).
//  - Output: per (b,o) 8 contiguous locs -> float2 stores (fixes 3.5x write amp).

#define OW 62
#define LOCS 3844
#define WSTRIDE_I 34596u   // 62*62*9
#define XM 131072u         // 32*64*64 elements per batch image

__global__ void lc2d_transpose_x(const float* __restrict__ x, float* __restrict__ xT) {
    __shared__ float tile[64][65];
    const int m0 = blockIdx.x * 64;
    const int t = threadIdx.x;
    const int c = t & 63, q = t >> 6;   // q in 0..3
#pragma unroll
    for (int j = 0; j < 16; ++j) {
        const int b = q * 16 + j;
        tile[c][b] = x[(size_t)b * XM + (size_t)(m0 + c)];
    }
    __syncthreads();
#pragma unroll
    for (int j = 0; j < 16; ++j) {
        const int m = q * 16 + j;
        xT[(size_t)(m0 + m) * 64u + (size_t)c] = tile[m][c];
    }
}

__global__ __launch_bounds__(512) void lc2d_main(const float* __restrict__ w,
                                                 const float* __restrict__ xT,
                                                 float* __restrict__ out) {
    // [buf][wave][o'][run padded to 128 floats]: 2*8*8*128*4B = 64 KiB
    __shared__ float Wl[2][8][8][128];

    const int bid = blockIdx.x;
    const int oh  = bid >> 3;
    const int t8  = bid & 7;
    const int ow0 = (t8 < 7) ? (t8 << 3) : 54;   // last tile overlaps (54..61) -> uniform 8-wide, no guards
    const int loc0 = oh * OW + ow0;

    const int lane = threadIdx.x & 63;                                   // = b
    const int g = __builtin_amdgcn_readfirstlane((int)(threadIdx.x >> 6)); // wave -> o-group
    const int lclamp = (lane > 7) ? 7 : lane;                            // tail-32B clamp

    // stage weight runs for channel i into LDS buffer ib (this wave's 8 o's only)
    auto stage = [&](int ib, int i) {
#pragma unroll
        for (int op = 0; op < 8; ++op) {
            const size_t rb = (size_t)((g * 8 + op) * 32 + i) * WSTRIDE_I + (size_t)loc0 * 9u;
            const float* g1 = w + rb + (size_t)lane;          // floats 0..63
            const float* g2 = w + rb + 64u + (size_t)lclamp;  // floats 64..71 (lanes>=8 dup 71 -> pad)
            __builtin_amdgcn_global_load_lds(
                (const __attribute__((address_space(1))) unsigned int*)g1,
                (__attribute__((address_space(3))) unsigned int*)&Wl[ib][g][op][0], 4, 0, 0);
            __builtin_amdgcn_global_load_lds(
                (const __attribute__((address_space(1))) unsigned int*)g2,
                (__attribute__((address_space(3))) unsigned int*)&Wl[ib][g][op][64], 4, 0, 0);
        }
    };

    float acc[8][8];   // [o'][loc']
#pragma unroll
    for (int a = 0; a < 8; ++a)
#pragma unroll
        for (int bb = 0; bb < 8; ++bb) acc[a][bb] = 0.f;

    stage(0, 0);

#pragma unroll 1
    for (int i = 0; i < 32; ++i) {
        // x taps for this channel: xr[r][c], c in 0..9 (coalesced dword, L1-hot across waves)
        float xr[30];
        const float* xp = xT + ((size_t)i * 4096u + (size_t)oh * 64u + (size_t)ow0) * 64u + (size_t)lane;
#pragma unroll
        for (int r = 0; r < 3; ++r)
#pragma unroll
            for (int c = 0; c < 10; ++c)
                xr[r * 10 + c] = xp[(size_t)((r * 64 + c) * 64)];

        if (i < 31) stage((i + 1) & 1, i + 1);   // fire next slab (16 async DMAs)

        // counted wait: leave exactly the 16 next-slab DMAs in flight;
        // guarantees prev slab (older) + xr have landed.
        asm volatile("s_waitcnt vmcnt(16)" ::: "memory");
        __builtin_amdgcn_sched_barrier(0);

        const int ib = i & 1;
#pragma unroll
        for (int op = 0; op < 8; ++op) {
            const float* wrow = &Wl[ib][g][op][0];
#pragma unroll
            for (int q = 0; q < 18; ++q) {
                const float4 wq = *(const float4*)(wrow + (q << 2));  // same-addr b128 broadcast
#pragma unroll
                for (int u = 0; u < 4; ++u) {
                    const int f = (q << 2) + u;      // 0..71
                    const int l = f / 9;             // loc'
                    const int k = f - 9 * l;         // tap
                    const float wf = (u == 0) ? wq.x : (u == 1) ? wq.y : (u == 2) ? wq.z : wq.w;
                    acc[op][l] = fmaf(wf, xr[(k / 3) * 10 + l + (k % 3)], acc[op][l]);
                }
            }
        }
    }

    // out[b][o][loc0..loc0+7]: contiguous 8 floats per (b,o) -> float2 stores (8B-aligned)
#pragma unroll
    for (int op = 0; op < 8; ++op) {
        float* po = out + (size_t)(lane * 64 + g * 8 + op) * (size_t)LOCS + (size_t)loc0;
#pragma unroll
        for (int q = 0; q < 4; ++q) {
            float2 v = make_float2(acc[op][q * 2], acc[op][q * 2 + 1]);
            *(float2*)(po + q * 2) = v;
        }
    }
}

extern "C" void kernel_launch(void* const* d_in, const int* in_sizes, int n_in,
                              void* d_out, int out_size, void* d_ws, size_t ws_size,
                              hipStream_t stream) {
    const float* x = (const float*)d_in[0];   // 64*32*64*64
    const float* w = (const float*)d_in[1];   // 1*64*32*62*62*9
    float* out = (float*)d_out;               // 64*64*62*62
    float* xT = (float*)d_ws;                 // 32 MiB (verified available in round 1)

    lc2d_transpose_x<<<dim3(XM / 64), dim3(256), 0, stream>>>(x, xT);
    lc2d_main<<<dim3(496), dim3(512), 0, stream>>>(w, xT, out);
}